// Round 4
// baseline (207.333 us; speedup 1.0000x reference)
//
#include <hip/hip_runtime.h>
#include <math.h>

// CTC forward (keras ctc_batch_cost), B=1024 T=256 C=128 L=64, S=129.
// One wave64 per batch element, zero barriers.
//  - Memory: coalesced float4 staging of full prob rows into LDS (double
//    buffer, 2-chunk register prefetch pipeline); per-step probabilities come
//    from LDS (label gather ~2-way banks = free; blank = broadcast). This
//    replaces R2's 512 scattered global dword loads per wave (the bottleneck).
//  - Recurrence in probability domain (linear semiring), q=(p+eps)*128,
//    wave-uniform renorm every 8 steps (DPP max tree -> exponent into Esum).
//  - State layout: lane i owns states 2i (blank) and 2i+1 (label l_i);
//    state 128 rides on lane 63. Only ONE dpp wave_shr:1 per step (left
//    neighbor's odd state feeds both updates); lane-0 boundary comes free
//    from bound_ctrl=0.

#define Bn 1024
#define Tn 256
#define Cn 128
#define Ln 64
#define BLANK 127
#define U 8
#define NC (Tn / U)
#define EPS128 (1e-7f * 128.0f)
#define LN2 0.69314718055994530942f

template <int CTRL>
__device__ __forceinline__ float dpp_movf(float x) {
    return __int_as_float(__builtin_amdgcn_update_dpp(
        0, __float_as_int(x), CTRL, 0xF, 0xF, true));
}
__device__ __forceinline__ int dpp_shr1_i(int x) {
    return __builtin_amdgcn_update_dpp(0, x, 0x138, 0xF, 0xF, true);
}

__global__ __launch_bounds__(64)
void ctc_lds_kernel(const int* __restrict__ y_true,
                    const float* __restrict__ y_pred,
                    float* __restrict__ out) {
    const int b = blockIdx.x;
    const int i = threadIdx.x;

    __shared__ __align__(16) float prob[2][U * Cn];   // 2 x 4 KB

    const int li = y_true[b * Ln + i];
    const int ll = dpp_shr1_i(li);                    // lab[i-1] (lane0: 0)
    const float skf = (li != ll) ? 1.0f : 0.0f;       // lane0's Ol is 0 anyway

    const float4* gsrc = (const float4*)(y_pred + (size_t)b * (Tn * Cn));
    float4 ra[4], rb[4];

    auto gload = [&](int c, float4* r) {
        const float4* p = gsrc + c * (U * Cn / 4) + i;
#pragma unroll
        for (int k = 0; k < 4; ++k) r[k] = p[k * 64];
    };
    auto lwrite = [&](int buf, const float4* r) {
        float4* d = ((float4*)prob[buf]) + i;
#pragma unroll
        for (int k = 0; k < 4; ++k) d[k * 64] = r[k];
    };

    float E = 0.f, O = 0.f, X = 0.f;   // states 2i, 2i+1, 128(lane63)
    int Esum = 0;

    auto steps = [&](const float* pr, bool first) {
#pragma unroll
        for (int j = 0; j < U; ++j) {
            const float* row = pr + j * Cn;
            const float ql = fmaf(row[li],    128.0f, EPS128);
            const float qb = fmaf(row[BLANK], 128.0f, EPS128);
            if (first && j == 0) {        // t=0: only states 0,1 reachable
                E = (i == 0) ? qb : 0.f;
                O = (i == 0) ? ql : 0.f;
                X = 0.f;
                continue;
            }
            const float Ol = dpp_movf<0x138>(O);      // state 2i-1 from left
            const float t1 = O + E;
            const float nO = fmaf(skf, Ol, t1) * ql;  // state 2i+1
            const float nE = (E + Ol) * qb;           // state 2i
            const float nX = (X + O) * qb;            // state 128 (lane63)
            E = nE; O = nO; X = nX;
        }
    };
    auto renorm = [&]() {
        float m = fmaxf(E, O);
        if (i == 63) m = fmaxf(m, X);
        m = fmaxf(m, dpp_movf<0x111>(m));   // row_shr:1
        m = fmaxf(m, dpp_movf<0x112>(m));   // row_shr:2
        m = fmaxf(m, dpp_movf<0x114>(m));   // row_shr:4
        m = fmaxf(m, dpp_movf<0x118>(m));   // row_shr:8
        m = fmaxf(m, dpp_movf<0x142>(m));   // row_bcast:15
        m = fmaxf(m, dpp_movf<0x143>(m));   // row_bcast:31 -> lane63 = wave max
        const unsigned ub =
            (unsigned)__builtin_amdgcn_readlane(__float_as_int(m), 63);
        const int eb = (int)(ub >> 23);
        const float sc = __int_as_float((unsigned)(254 - eb) << 23);
        Esum += eb - 127;
        E *= sc; O *= sc; X *= sc;
    };

    // staging pipeline: 2 chunks of cover for global latency
    gload(0, ra);
    gload(1, rb);
    lwrite(0, ra);
    gload(2, ra);

    for (int c = 0; c < NC; c += 2) {
        lwrite(1, rb);                       // chunk c+1 (loaded ~1 iter ago)
        if (c + 3 < NC) gload(c + 3, rb);
        steps(prob[0], c == 0);              // chunk c
        renorm();
        lwrite(0, ra);                       // chunk c+2
        if (c + 4 < NC) gload(c + 4, ra);
        steps(prob[1], false);               // chunk c+1
        if (c + 2 < NC) renorm();            // skip after final chunk
    }

    if (i == 63) {
        const float s = O + X;               // alpha[127] + alpha[128]
#if __has_builtin(__builtin_amdgcn_logf)
        const float l2 = __builtin_amdgcn_logf(s);
#else
        const float l2 = log2f(s);
#endif
        out[b] = -(l2 + (float)(Esum - 7 * Tn)) * LN2;
    }
}

extern "C" void kernel_launch(void* const* d_in, const int* in_sizes, int n_in,
                              void* d_out, int out_size, void* d_ws, size_t ws_size,
                              hipStream_t stream) {
    const int*   y_true = (const int*)d_in[0];
    const float* y_pred = (const float*)d_in[1];
    float*       out    = (float*)d_out;
    hipLaunchKernelGGL(ctc_lds_kernel, dim3(Bn), dim3(64), 0, stream,
                       y_true, y_pred, out);
}

// Round 5
// 191.877 us; speedup vs baseline: 1.0805x; 1.0805x over previous
//
#include <hip/hip_runtime.h>
#include <math.h>

// CTC forward (keras ctc_batch_cost), B=1024 T=256 C=128 L=64, S=129.
// One wave64 per batch element, zero barriers. R5: deep async pipeline.
//  - global_load_lds (16B/lane, 4 instrs per 4KB chunk) into an 8-slot LDS
//    ring; 7 chunks (56 timesteps, 28 loads) kept in flight; manual
//    s_waitcnt vmcnt(20) per chunk (never drains the queue until the tail).
//    This hides ~900cy HBM latency that R2/R4 exposed per chunk (d_ws poison
//    evicts L3 every timed iteration -> y_pred is HBM-cold).
//  - q-values (label gather + blank) register-prefetched one chunk ahead of
//    the recurrence, so the per-step chain is pure VALU + one DPP shift.
//  - Probability-domain semiring recurrence with x128 bias and wave-uniform
//    renorm every 8 steps (exponent stripped into Esum) -- verified absmax 0.

#define Bn 1024
#define Tn 256
#define Cn 128
#define Ln 64
#define BLANK 127
#define U 8
#define NC (Tn / U)       // 32 chunks
#define RING 8
#define DEPTH 7           // chunks in flight: 7*4 = 28 loads <= 63
#define EPS128 (1e-7f * 128.0f)
#define LN2 0.69314718055994530942f

// s_waitcnt imm: vmcnt bits [3:0]+[15:14]; expcnt[6:4]=7, lgkmcnt[11:8]=0xF don't-care
#define WAIT_VM(n) __builtin_amdgcn_s_waitcnt((((n) & 0xF) | (((n) >> 4) << 14)) | 0x0F70)
#define SCHED_FENCE() __builtin_amdgcn_sched_barrier(0)

template <int CTRL>
__device__ __forceinline__ float dpp_movf(float x) {
    return __int_as_float(__builtin_amdgcn_update_dpp(
        0, __float_as_int(x), CTRL, 0xF, 0xF, true));
}
__device__ __forceinline__ int dpp_shr1_i(int x) {
    return __builtin_amdgcn_update_dpp(0, x, 0x138, 0xF, 0xF, true);
}
__device__ __forceinline__ void dma16(const float* g, float* l) {
    __builtin_amdgcn_global_load_lds(
        (const __attribute__((address_space(1))) void*)g,
        (__attribute__((address_space(3))) void*)l, 16, 0, 0);
}

__global__ __launch_bounds__(64)
void ctc_ring_kernel(const int* __restrict__ y_true,
                     const float* __restrict__ y_pred,
                     float* __restrict__ out) {
    __shared__ __align__(16) float ring[RING][U * Cn];   // 32 KB
    const int b = blockIdx.x;
    const int i = threadIdx.x;

    const int li = y_true[b * Ln + i];
    const int ll = dpp_shr1_i(li);                 // lab[i-1] (lane0 -> 0)
    const float skf = (li != ll) ? 1.0f : 0.0f;

    const float* gb = y_pred + (size_t)b * (Tn * Cn);

    auto issue_chunk = [&](int c) {
        const float* g = gb + c * (U * Cn);
        float* l = ring[c & (RING - 1)];
#pragma unroll
        for (int k = 0; k < 4; ++k)                // 4 x (64 lanes x 16B) = 4 KB
            dma16(g + k * 256 + i * 4, l + k * 256);
    };

    float qlA[U], qbA[U], qlB[U], qbB[U];
    auto qread = [&](int c, float* ql, float* qb) {
        const float* s = ring[c & (RING - 1)];
#pragma unroll
        for (int j = 0; j < U; ++j) {
            ql[j] = fmaf(s[j * Cn + li],    128.0f, EPS128);
            qb[j] = fmaf(s[j * Cn + BLANK], 128.0f, EPS128);
        }
    };

    float E = 0.f, O = 0.f, X = 0.f;   // states 2i, 2i+1, 128(lane63)
    int Esum = 0;

    auto steps = [&](const float* ql, const float* qb, bool first) {
#pragma unroll
        for (int j = 0; j < U; ++j) {
            if (first && j == 0) {                 // t=0: only states 0,1
                E = (i == 0) ? qb[0] : 0.f;
                O = (i == 0) ? ql[0] : 0.f;
                X = 0.f;
                continue;
            }
            const float Ol = dpp_movf<0x138>(O);   // state 2i-1 from left
            const float t1 = O + E;
            const float nO = fmaf(skf, Ol, t1) * ql[j];
            const float nE = (E + Ol) * qb[j];
            const float nX = (X + O) * qb[j];
            E = nE; O = nO; X = nX;
        }
    };
    auto renorm = [&]() {
        float m = fmaxf(E, O);
        if (i == 63) m = fmaxf(m, X);
        m = fmaxf(m, dpp_movf<0x111>(m));
        m = fmaxf(m, dpp_movf<0x112>(m));
        m = fmaxf(m, dpp_movf<0x114>(m));
        m = fmaxf(m, dpp_movf<0x118>(m));
        m = fmaxf(m, dpp_movf<0x142>(m));
        m = fmaxf(m, dpp_movf<0x143>(m));          // lane63 = wave max
        const unsigned ub =
            (unsigned)__builtin_amdgcn_readlane(__float_as_int(m), 63);
        const int eb = (int)(ub >> 23);
        const float sc = __int_as_float((unsigned)(254 - eb) << 23);
        Esum += eb - 127;
        E *= sc; O *= sc; X *= sc;
    };

    // ---- prologue: fill the pipe (chunks 0..6 in flight) ----
#pragma unroll
    for (int c = 0; c < DEPTH; ++c) issue_chunk(c);
    WAIT_VM(24);                     // chunk 0 landed (24 loads still out)
    SCHED_FENCE();
    qread(0, qlA, qbA);

    // ---- steady state: chunks 0..23, issue stays 7 ahead ----
    for (int cc = 0; cc < 24; cc += 2) {
        WAIT_VM(20); SCHED_FENCE();  // chunk cc+1 landed
        qread(cc + 1, qlB, qbB);
        issue_chunk(cc + 7);
        steps(qlA, qbA, cc == 0);    // chunk cc
        renorm();
        WAIT_VM(20); SCHED_FENCE();  // chunk cc+2 landed
        qread(cc + 2, qlA, qbA);
        issue_chunk(cc + 8);
        steps(qlB, qbB, false);      // chunk cc+1
        renorm();
    }
    // issued through 30; completed through 24; qA = chunk 24
    WAIT_VM(20); SCHED_FENCE();      // chunk 25 landed
    qread(25, qlB, qbB);
    issue_chunk(31);
    steps(qlA, qbA, false);          // 24
    renorm();
    WAIT_VM(0); SCHED_FENCE();       // drain: chunks 26..31 all in LDS
    qread(26, qlA, qbA);
    steps(qlB, qbB, false);          // 25
    renorm();
    qread(27, qlB, qbB); steps(qlA, qbA, false); renorm();   // 26
    qread(28, qlA, qbA); steps(qlB, qbB, false); renorm();   // 27
    qread(29, qlB, qbB); steps(qlA, qbA, false); renorm();   // 28
    qread(30, qlA, qbA); steps(qlB, qbB, false); renorm();   // 29
    qread(31, qlB, qbB); steps(qlA, qbA, false); renorm();   // 30
    steps(qlB, qbB, false);                                   // 31

    if (i == 63) {
        const float s = O + X;       // alpha[127] + alpha[128] (scaled)
#if __has_builtin(__builtin_amdgcn_logf)
        const float l2 = __builtin_amdgcn_logf(s);
#else
        const float l2 = log2f(s);
#endif
        out[b] = -(l2 + (float)(Esum - 7 * Tn)) * LN2;
    }
}

extern "C" void kernel_launch(void* const* d_in, const int* in_sizes, int n_in,
                              void* d_out, int out_size, void* d_ws, size_t ws_size,
                              hipStream_t stream) {
    const int*   y_true = (const int*)d_in[0];
    const float* y_pred = (const float*)d_in[1];
    float*       out    = (float*)d_out;
    hipLaunchKernelGGL(ctc_ring_kernel, dim3(Bn), dim3(64), 0, stream,
                       y_true, y_pred, out);
}